// Round 1
// baseline (489.327 us; speedup 1.0000x reference)
//
#include <hip/hip_runtime.h>
#include <math.h>

#define IN_DIM 28
#define BOND   10
#define OUT_D  10

// One thread = one sample.
//  - x loads: 14 x global_load_dwordx4 per thread (contiguous 224 B/sample).
//  - t0/t1/bias accessed with uniform indices -> compiler scalarizes to s_load,
//    weights live in SGPRs / scalar cache (11 KB fits K$), FMAs are v*s+v.
//  - ~3360 fp32 FMA per sample; no LDS at all.
__global__ __launch_bounds__(256) void tn_layer_kernel(
    const float* __restrict__ x,     // [N, 56]
    const float* __restrict__ t0,    // [28, 10]
    const float* __restrict__ t1,    // [28, 10, 10]
    const float* __restrict__ bias,  // [10]
    float* __restrict__ out,         // [N, 10]
    int n_total)
{
    const int n = blockIdx.x * blockDim.x + threadIdx.x;
    if (n >= n_total) return;

    // ---- load the sample's 56 floats (fully coalesced over the 224 B row) ----
    const float4* __restrict__ xin =
        reinterpret_cast<const float4*>(x + (size_t)n * (2 * IN_DIM));
    float xs[2 * IN_DIM];
#pragma unroll
    for (int k = 0; k < 14; ++k) {
        float4 v = xin[k];
        xs[4 * k + 0] = v.x;
        xs[4 * k + 1] = v.y;
        xs[4 * k + 2] = v.z;
        xs[4 * k + 3] = v.w;
    }
    const float* x0 = xs;           // first unit
    const float* x1 = xs + IN_DIM;  // second unit

    // ---- h0[b] = sum_i x0[i] * t0[i][b]  (280 FMA) ----
    float h0[BOND];
#pragma unroll
    for (int b = 0; b < BOND; ++b) h0[b] = 0.0f;
#pragma unroll
    for (int i = 0; i < IN_DIM; ++i) {
        const float xi = x0[i];
#pragma unroll
        for (int b = 0; b < BOND; ++b)
            h0[b] = fmaf(xi, t0[i * BOND + b], h0[b]);
    }

    // ---- c[o] = sum_b sum_j (h0[b]*x1[j]) * t1[j][b][o]  (~3080 FMA) ----
    float c[OUT_D];
#pragma unroll
    for (int o = 0; o < OUT_D; ++o) c[o] = bias[o];

    // unroll-2 on b keeps the live scalar-weight window ~2*28*10 regs worth of
    // s_loads in flight without blowing the SGPR file.
#pragma unroll 2
    for (int b = 0; b < BOND; ++b) {
        const float hb = h0[b];
#pragma unroll
        for (int j = 0; j < IN_DIM; ++j) {
            const float p = x1[j] * hb;                      // 1 mul
            const float* __restrict__ w = t1 + (j * BOND + b) * OUT_D;
#pragma unroll
            for (int o = 0; o < OUT_D; ++o)                  // 10 FMA (v,s,v)
                c[o] = fmaf(p, w[o], c[o]);
        }
    }

    // ---- sigmoid + store (out row = 40 B, 8-aligned -> 5x float2 stores) ----
    float2* __restrict__ op = reinterpret_cast<float2*>(out + (size_t)n * OUT_D);
#pragma unroll
    for (int o = 0; o < OUT_D; o += 2) {
        float2 r;
        r.x = 1.0f / (1.0f + __expf(-c[o]));
        r.y = 1.0f / (1.0f + __expf(-c[o + 1]));
        op[o >> 1] = r;
    }
}

extern "C" void kernel_launch(void* const* d_in, const int* in_sizes, int n_in,
                              void* d_out, int out_size, void* d_ws, size_t ws_size,
                              hipStream_t stream) {
    const float* x    = (const float*)d_in[0];  // [N, 56]
    const float* t0   = (const float*)d_in[1];  // [28,10]
    const float* t1   = (const float*)d_in[2];  // [28,10,10]
    const float* bias = (const float*)d_in[3];  // [10]
    float* out        = (float*)d_out;          // [N, 10]

    const int n_total = in_sizes[0] / (2 * IN_DIM);
    const int block = 256;
    const int grid = (n_total + block - 1) / block;
    tn_layer_kernel<<<grid, block, 0, stream>>>(x, t0, t1, bias, out, n_total);
}

// Round 2
// 351.898 us; speedup vs baseline: 1.3905x; 1.3905x over previous
//
#include <hip/hip_runtime.h>
#include <math.h>

#define IN_DIM 28
#define BOND   10
#define OUT_D  10
#define BLOCK  256
#define H0_STRIDE 11   // odd stride -> conflict-free per-thread h0 slots

// One thread = one sample. Weights live in LDS; every weight read is a
// ds_read_b128 broadcast (all lanes same addr) at an immediate offset ->
// zero address-calc VALU. All register arrays are indexed with compile-time
// constants except h0[b] (runtime b in the rolled b-loop), which round-trips
// through LDS at odd stride (conflict-free).
__global__ __launch_bounds__(BLOCK) void tn_kernel(
    const float* __restrict__ x,     // [N, 56]
    const float* __restrict__ t0,    // [28,10]
    const float* __restrict__ t1,    // [28,10,10]
    const float* __restrict__ bias,  // [10]
    float* __restrict__ out,         // [N,10]
    int n_total)
{
    __shared__ __align__(16) float lt0[IN_DIM * BOND];          // 280, [i][b]
    __shared__ __align__(16) float lt1[BOND * IN_DIM * OUT_D];  // 2800, repacked [b][j][o]
    __shared__ float lbias[OUT_D];
    __shared__ float lh0[BLOCK * H0_STRIDE];                    // per-thread h0 spill

    const int tid = threadIdx.x;

    // ---- cooperative staging (one-time; int div by constants -> magic mul) ----
    for (int idx = tid; idx < IN_DIM * BOND; idx += BLOCK)
        lt0[idx] = t0[idx];
    for (int idx = tid; idx < BOND * IN_DIM * OUT_D; idx += BLOCK) {
        const int b = idx / (IN_DIM * OUT_D);
        const int r = idx - b * (IN_DIM * OUT_D);
        const int j = r / OUT_D;
        const int o = r - j * OUT_D;
        lt1[idx] = t1[(j * BOND + b) * OUT_D + o];   // [j][b][o] -> [b][j][o]
    }
    if (tid < OUT_D) lbias[tid] = bias[tid];

    const int n = blockIdx.x * BLOCK + tid;   // grid is exact: N % 256 == 0

    // ---- load this sample's 56 floats (14 float4; row = 224 B, 16-aligned) ----
    float4 xq[14];
    const float4* __restrict__ xrow =
        reinterpret_cast<const float4*>(x + (size_t)n * (2 * IN_DIM));
#pragma unroll
    for (int k = 0; k < 14; ++k) xq[k] = xrow[k];

    __syncthreads();

    // unpack to a compile-time-indexed register array
    float xe[2 * IN_DIM];
#pragma unroll
    for (int k = 0; k < 14; ++k) {
        xe[4 * k + 0] = xq[k].x;
        xe[4 * k + 1] = xq[k].y;
        xe[4 * k + 2] = xq[k].z;
        xe[4 * k + 3] = xq[k].w;
    }

    // ---- h0[b] = sum_i x0[i] * t0[i][b] : 70 b128 broadcasts + 280 FMA ----
    float h0[BOND];
#pragma unroll
    for (int b = 0; b < BOND; ++b) h0[b] = 0.0f;
    {
        const float4* __restrict__ w0 = reinterpret_cast<const float4*>(lt0);
#pragma unroll
        for (int c = 0; c < 70; ++c) {
            const float4 w = w0[c];
            const int f = 4 * c;
            h0[(f + 0) % 10] = fmaf(xe[(f + 0) / 10], w.x, h0[(f + 0) % 10]);
            h0[(f + 1) % 10] = fmaf(xe[(f + 1) / 10], w.y, h0[(f + 1) % 10]);
            h0[(f + 2) % 10] = fmaf(xe[(f + 2) / 10], w.z, h0[(f + 2) % 10]);
            h0[(f + 3) % 10] = fmaf(xe[(f + 3) / 10], w.w, h0[(f + 3) % 10]);
        }
    }
    // spill h0 so the rolled b-loop can index it at runtime without scratch
#pragma unroll
    for (int b = 0; b < BOND; ++b) lh0[tid * H0_STRIDE + b] = h0[b];

    // ---- c[o] = bias[o] + sum_b h0[b] * (sum_j x1[j] * t1[j][b][o]) ----
    float acc[OUT_D];
#pragma unroll
    for (int o = 0; o < OUT_D; ++o) acc[o] = lbias[o];

#pragma unroll 1   // keep rolled: body ~3 KB, stays in L1I
    for (int b = 0; b < BOND; ++b) {
        const float hb = lh0[tid * H0_STRIDE + b];
        const float4* __restrict__ wb =
            reinterpret_cast<const float4*>(&lt1[b * (IN_DIM * OUT_D)]);
        float h1[OUT_D];
#pragma unroll
        for (int o = 0; o < OUT_D; ++o) h1[o] = 0.0f;
#pragma unroll
        for (int c = 0; c < 70; ++c) {
            const float4 w = wb[c];
            const int f = 4 * c;
            h1[(f + 0) % 10] = fmaf(xe[28 + (f + 0) / 10], w.x, h1[(f + 0) % 10]);
            h1[(f + 1) % 10] = fmaf(xe[28 + (f + 1) / 10], w.y, h1[(f + 1) % 10]);
            h1[(f + 2) % 10] = fmaf(xe[28 + (f + 2) / 10], w.z, h1[(f + 2) % 10]);
            h1[(f + 3) % 10] = fmaf(xe[28 + (f + 3) / 10], w.w, h1[(f + 3) % 10]);
        }
#pragma unroll
        for (int o = 0; o < OUT_D; ++o) acc[o] = fmaf(hb, h1[o], acc[o]);
    }

    // ---- sigmoid + store (row = 40 B, 8-aligned -> 5 float2 stores) ----
    if (n < n_total) {
        float2* __restrict__ op =
            reinterpret_cast<float2*>(out + (size_t)n * OUT_D);
#pragma unroll
        for (int o = 0; o < OUT_D; o += 2) {
            float2 r;
            r.x = 1.0f / (1.0f + __expf(-acc[o]));
            r.y = 1.0f / (1.0f + __expf(-acc[o + 1]));
            op[o >> 1] = r;
        }
    }
}

extern "C" void kernel_launch(void* const* d_in, const int* in_sizes, int n_in,
                              void* d_out, int out_size, void* d_ws, size_t ws_size,
                              hipStream_t stream) {
    const float* x    = (const float*)d_in[0];
    const float* t0   = (const float*)d_in[1];
    const float* t1   = (const float*)d_in[2];
    const float* bias = (const float*)d_in[3];
    float* out        = (float*)d_out;

    const int n_total = in_sizes[0] / (2 * IN_DIM);
    const int grid = (n_total + BLOCK - 1) / BLOCK;
    tn_kernel<<<grid, BLOCK, 0, stream>>>(x, t0, t1, bias, out, n_total);
}